// Round 1
// baseline (6372.495 us; speedup 1.0000x reference)
//
#include <hip/hip_runtime.h>

// GEMM [N,D]@[D,V] fp32 + fused row-argmax.
// Block tile: BM x BN = 128x128, BK=16, 256 threads, 8x8 micro-tile/thread.
// Cross-block argmax via packed u64 atomicMax in d_ws (key = monotonic
// float bits in high 32, ~col in low 32 so ties pick the LOWEST column,
// matching np.argmax first-occurrence semantics).

#define BM 128
#define BN 128
#define BK 16
#define TM 8
#define TN 8

__device__ __forceinline__ unsigned int fkey(float f) {
    unsigned int u = __float_as_uint(f);
    return u ^ ((u & 0x80000000u) ? 0xFFFFFFFFu : 0x80000000u);
}

__global__ __launch_bounds__(256) void gemm_argmax_kernel(
    const float* __restrict__ A,   // [N][D]
    const float* __restrict__ B,   // [D][V]
    unsigned long long* __restrict__ best,  // [N] packed (key, ~col)
    int N, int D, int V)
{
    __shared__ float As[BK][BM + 4];   // transposed A tile, padded
    __shared__ float Bs[BK][BN + 4];   // B tile, padded

    const int tid = threadIdx.x;
    const int tx = tid & 15;           // col group 0..15
    const int ty = tid >> 4;           // row group 0..15
    const int bm = blockIdx.y * BM;
    const int bn = blockIdx.x * BN;

    // A-load mapping: 2 float4 per thread per K-step
    const int arow  = tid >> 2;        // 0..63
    const int acol4 = tid & 3;         // 0..3 (float4 index within 16 cols)
    // B-load mapping: 2 float4 per thread per K-step
    const int brow  = tid >> 5;        // 0..7
    const int bcol4 = tid & 31;        // 0..31

    float acc[TM][TN];
#pragma unroll
    for (int i = 0; i < TM; ++i)
#pragma unroll
        for (int j = 0; j < TN; ++j) acc[i][j] = 0.0f;

    for (int k0 = 0; k0 < D; k0 += BK) {
        // ---- load A tile [BM][BK] -> As[BK][BM] (transposed) ----
        float4 a0 = *reinterpret_cast<const float4*>(
            &A[(size_t)(bm + arow) * D + k0 + acol4 * 4]);
        float4 a1 = *reinterpret_cast<const float4*>(
            &A[(size_t)(bm + arow + 64) * D + k0 + acol4 * 4]);
        // ---- load B tile [BK][BN] -> Bs ----
        float4 b0 = *reinterpret_cast<const float4*>(
            &B[(size_t)(k0 + brow) * V + bn + bcol4 * 4]);
        float4 b1 = *reinterpret_cast<const float4*>(
            &B[(size_t)(k0 + brow + 8) * V + bn + bcol4 * 4]);

        As[acol4 * 4 + 0][arow] = a0.x;
        As[acol4 * 4 + 1][arow] = a0.y;
        As[acol4 * 4 + 2][arow] = a0.z;
        As[acol4 * 4 + 3][arow] = a0.w;
        As[acol4 * 4 + 0][arow + 64] = a1.x;
        As[acol4 * 4 + 1][arow + 64] = a1.y;
        As[acol4 * 4 + 2][arow + 64] = a1.z;
        As[acol4 * 4 + 3][arow + 64] = a1.w;
        *reinterpret_cast<float4*>(&Bs[brow][bcol4 * 4]) = b0;
        *reinterpret_cast<float4*>(&Bs[brow + 8][bcol4 * 4]) = b1;

        __syncthreads();

#pragma unroll
        for (int kk = 0; kk < BK; ++kk) {
            float4 av0 = *reinterpret_cast<const float4*>(&As[kk][ty * TM]);
            float4 av1 = *reinterpret_cast<const float4*>(&As[kk][ty * TM + 4]);
            float4 bv0 = *reinterpret_cast<const float4*>(&Bs[kk][tx * TN]);
            float4 bv1 = *reinterpret_cast<const float4*>(&Bs[kk][tx * TN + 4]);
            float a[TM] = {av0.x, av0.y, av0.z, av0.w, av1.x, av1.y, av1.z, av1.w};
            float b[TN] = {bv0.x, bv0.y, bv0.z, bv0.w, bv1.x, bv1.y, bv1.z, bv1.w};
#pragma unroll
            for (int i = 0; i < TM; ++i)
#pragma unroll
                for (int j = 0; j < TN; ++j)
                    acc[i][j] = fmaf(a[i], b[j], acc[i][j]);
        }
        __syncthreads();
    }

    // ---- fused argmax epilogue ----
    // Each thread: rows bm + ty*TM + i, cols bn + tx*TN + j.
#pragma unroll
    for (int i = 0; i < TM; ++i) {
        float bv = acc[i][0];
        int bc = bn + tx * TN;
#pragma unroll
        for (int j = 1; j < TN; ++j) {
            float v = acc[i][j];
            int c = bn + tx * TN + j;
            if (v > bv) { bv = v; bc = c; }   // strict > keeps lowest col
        }
        unsigned long long packed =
            ((unsigned long long)fkey(bv) << 32) |
            (unsigned long long)(0xFFFFFFFFu - (unsigned int)bc);
        // reduce across the 16 tx lanes (contiguous lanes within a wave)
#pragma unroll
        for (int m = 1; m < 16; m <<= 1) {
            unsigned long long o = __shfl_xor(packed, m, 16);
            if (o > packed) packed = o;
        }
        if (tx == 0) {
            atomicMax(&best[bm + ty * TM + i], packed);
        }
    }
}

__global__ void decode_kernel(const unsigned long long* __restrict__ best,
                              float* __restrict__ out, int N)
{
    int i = blockIdx.x * blockDim.x + threadIdx.x;
    if (i < N) {
        unsigned int inv = (unsigned int)(best[i] & 0xFFFFFFFFull);
        out[i] = (float)(0xFFFFFFFFu - inv);
    }
}

extern "C" void kernel_launch(void* const* d_in, const int* in_sizes, int n_in,
                              void* d_out, int out_size, void* d_ws, size_t ws_size,
                              hipStream_t stream) {
    const float* A = (const float*)d_in[0];   // x  [N, D]
    const float* B = (const float*)d_in[1];   // di [D, V]
    float* out = (float*)d_out;

    const int N = out_size;                   // 16384
    const int D = in_sizes[0] / N;            // 2048
    const int V = in_sizes[1] / D;            // 8192

    unsigned long long* best = (unsigned long long*)d_ws;
    hipMemsetAsync(best, 0, (size_t)N * sizeof(unsigned long long), stream);

    dim3 grid(V / BN, N / BM);                // (64, 128)
    gemm_argmax_kernel<<<grid, 256, 0, stream>>>(A, B, best, N, D, V);
    decode_kernel<<<(N + 255) / 256, 256, 0, stream>>>(best, out, N);
}

// Round 2
// 6015.810 us; speedup vs baseline: 1.0593x; 1.0593x over previous
//
#include <hip/hip_runtime.h>

typedef _Float16 f16x8 __attribute__((ext_vector_type(8)));
typedef float f32x4 __attribute__((ext_vector_type(4)));

#define BM 128
#define BN 128

__device__ __forceinline__ unsigned int fkey(float f) {
    unsigned int u = __float_as_uint(f);
    return u ^ ((u & 0x80000000u) ? 0xFFFFFFFFu : 0x80000000u);
}

// ============================================================
// Prep: split fp32 -> (hi, lo) f16 pairs. x kept row-major; di transposed.
// ============================================================
__global__ __launch_bounds__(256) void prep_x_kernel(
    const float* __restrict__ x, _Float16* __restrict__ Xh,
    _Float16* __restrict__ Xl)
{
    size_t base = ((size_t)blockIdx.x * 256 + threadIdx.x) * 8;
    float4 a0 = *(const float4*)(x + base);
    float4 a1 = *(const float4*)(x + base + 4);
    float v[8] = {a0.x, a0.y, a0.z, a0.w, a1.x, a1.y, a1.z, a1.w};
    f16x8 h, l;
#pragma unroll
    for (int j = 0; j < 8; ++j) {
        _Float16 hh = (_Float16)v[j];
        h[j] = hh;
        l[j] = (_Float16)(v[j] - (float)hh);   // Sterbenz: residual exact in fp32
    }
    *(f16x8*)(Xh + base) = h;
    *(f16x8*)(Xl + base) = l;
}

__global__ __launch_bounds__(256) void prep_di_kernel(
    const float* __restrict__ di, _Float16* __restrict__ DhT,
    _Float16* __restrict__ DlT, int D, int V)
{
    // block covers 64 v-cols x 32 d-rows; thread: v = t&63, 8 d's at (t>>6)*8
    int v  = blockIdx.x * 64 + (threadIdx.x & 63);
    int d0 = blockIdx.y * 32 + (threadIdx.x >> 6) * 8;
    f16x8 h, l;
#pragma unroll
    for (int j = 0; j < 8; ++j) {
        float val = di[(size_t)(d0 + j) * V + v];   // coalesced across lanes
        _Float16 hh = (_Float16)val;
        h[j] = hh;
        l[j] = (_Float16)(val - (float)hh);
    }
    *(f16x8*)(DhT + (size_t)v * D + d0) = h;   // 16B store, coalesced-ish
    *(f16x8*)(DlT + (size_t)v * D + d0) = l;
}

// ============================================================
// Main: 128x128 tile, BK=32 f16, 4 waves (2x2), 4x4 16x16x32 frags/wave,
// 3 MFMA terms per frag pair. XOR-swizzled LDS (slot ^= row&3) so the
// 64B-row-stride frag reads are ~2-way (free) instead of 8-way.
// ============================================================
__global__ __launch_bounds__(256) void gemm_f16x3_argmax_kernel(
    const _Float16* __restrict__ Xh, const _Float16* __restrict__ Xl,
    const _Float16* __restrict__ DhT, const _Float16* __restrict__ DlT,
    unsigned long long* __restrict__ best, int N, int D, int V)
{
    __shared__ __align__(16) unsigned char sm[4 * 128 * 64]; // Ah,Al,Bh,Bl 8KB each

    const int tid = threadIdx.x;
    const int bm = blockIdx.y * BM;
    const int bn = blockIdx.x * BN;
    const int lane = tid & 63;
    const int w  = tid >> 6;
    const int wr = w >> 1, wc = w & 1;
    const int lm = lane & 15, lg = lane >> 4;

    const int srow  = tid >> 1;   // staging row 0..127
    const int shalf = tid & 1;    // which 32B half of the 64B row

    const _Float16* gA0 = Xh  + (size_t)(bm + srow) * D + shalf * 16;
    const _Float16* gA1 = Xl  + (size_t)(bm + srow) * D + shalf * 16;
    const _Float16* gB0 = DhT + (size_t)(bn + srow) * D + shalf * 16;
    const _Float16* gB1 = DlT + (size_t)(bn + srow) * D + shalf * 16;

    uint4 pre[8];
    auto load8 = [&](int k0) {
        const uint4* pA0 = (const uint4*)(gA0 + k0);
        const uint4* pA1 = (const uint4*)(gA1 + k0);
        const uint4* pB0 = (const uint4*)(gB0 + k0);
        const uint4* pB1 = (const uint4*)(gB1 + k0);
        pre[0] = pA0[0]; pre[1] = pA0[1];
        pre[2] = pA1[0]; pre[3] = pA1[1];
        pre[4] = pB0[0]; pre[5] = pB0[1];
        pre[6] = pB1[0]; pre[7] = pB1[1];
    };
    auto store8 = [&]() {
        const int sw = srow & 3;
#pragma unroll
        for (int a = 0; a < 4; ++a) {       // tile index: 0=Ah,1=Al,2=Bh,3=Bl
#pragma unroll
            for (int q = 0; q < 2; ++q) {
                int s  = shalf * 2 + q;     // logical 16B slot (k-group)
                int ss = s ^ sw;            // physical slot
                *(uint4*)(sm + a * 8192 + srow * 64 + ss * 16) = pre[a * 2 + q];
            }
        }
    };
    auto ldfrag = [&](int tile, int row) -> f16x8 {
        int ss = lg ^ (row & 3);
        return *(const f16x8*)(sm + tile * 8192 + row * 64 + ss * 16);
    };

    f32x4 acc[4][4];
#pragma unroll
    for (int fm = 0; fm < 4; ++fm)
#pragma unroll
        for (int fn = 0; fn < 4; ++fn) acc[fm][fn] = (f32x4){0.f, 0.f, 0.f, 0.f};

    load8(0);
    for (int k0 = 0; k0 < D; k0 += 32) {
        __syncthreads();          // previous compute done; LDS reusable
        store8();
        __syncthreads();          // tiles ready
        if (k0 + 32 < D) load8(k0 + 32);   // prefetch overlaps ds_read+MFMA

        f16x8 ah[4], al[4], bh[4], bl[4];
#pragma unroll
        for (int f = 0; f < 4; ++f) {
            int ar = wr * 64 + f * 16 + lm;
            int br = wc * 64 + f * 16 + lm;
            ah[f] = ldfrag(0, ar);
            al[f] = ldfrag(1, ar);
            bh[f] = ldfrag(2, br);
            bl[f] = ldfrag(3, br);
        }
#pragma unroll
        for (int fm = 0; fm < 4; ++fm)
#pragma unroll
            for (int fn = 0; fn < 4; ++fn) {
                acc[fm][fn] = __builtin_amdgcn_mfma_f32_16x16x32_f16(ah[fm], bh[fn], acc[fm][fn], 0, 0, 0);
                acc[fm][fn] = __builtin_amdgcn_mfma_f32_16x16x32_f16(ah[fm], bl[fn], acc[fm][fn], 0, 0, 0);
                acc[fm][fn] = __builtin_amdgcn_mfma_f32_16x16x32_f16(al[fm], bh[fn], acc[fm][fn], 0, 0, 0);
            }
    }

    // ---- fused argmax epilogue ----
    // C/D layout: col = lane&15, row = (lane>>4)*4 + j  (guide-verified, dtype-indep)
#pragma unroll
    for (int fm = 0; fm < 4; ++fm)
#pragma unroll
        for (int j = 0; j < 4; ++j) {
            int row = bm + wr * 64 + fm * 16 + lg * 4 + j;
            float bv = acc[fm][0][j];
            int   bc = bn + wc * 64 + lm;
#pragma unroll
            for (int fn = 1; fn < 4; ++fn) {
                float vv = acc[fm][fn][j];
                int   cc = bn + wc * 64 + fn * 16 + lm;
                if (vv > bv) { bv = vv; bc = cc; }   // strict > keeps lowest col
            }
            unsigned long long packed =
                ((unsigned long long)fkey(bv) << 32) |
                (unsigned long long)(0xFFFFFFFFu - (unsigned int)bc);
#pragma unroll
            for (int m = 1; m < 16; m <<= 1) {
                unsigned long long o = __shfl_xor(packed, m, 16);
                if (o > packed) packed = o;
            }
            if (lm == 0) atomicMax(&best[row], packed);
        }
}

// ============================================================
// Fallback (small ws): round-1 fp32 kernel, known-passing.
// ============================================================
#define FBK 16
#define FTM 8
#define FTN 8

__global__ __launch_bounds__(256) void gemm_argmax_fp32_kernel(
    const float* __restrict__ A, const float* __restrict__ B,
    unsigned long long* __restrict__ best, int N, int D, int V)
{
    __shared__ float As[FBK][BM + 4];
    __shared__ float Bs[FBK][BN + 4];

    const int tid = threadIdx.x;
    const int tx = tid & 15;
    const int ty = tid >> 4;
    const int bm = blockIdx.y * BM;
    const int bn = blockIdx.x * BN;

    const int arow  = tid >> 2;
    const int acol4 = tid & 3;
    const int brow  = tid >> 5;
    const int bcol4 = tid & 31;

    float acc[FTM][FTN];
#pragma unroll
    for (int i = 0; i < FTM; ++i)
#pragma unroll
        for (int j = 0; j < FTN; ++j) acc[i][j] = 0.0f;

    for (int k0 = 0; k0 < D; k0 += FBK) {
        float4 a0 = *reinterpret_cast<const float4*>(&A[(size_t)(bm + arow) * D + k0 + acol4 * 4]);
        float4 a1 = *reinterpret_cast<const float4*>(&A[(size_t)(bm + arow + 64) * D + k0 + acol4 * 4]);
        float4 b0 = *reinterpret_cast<const float4*>(&B[(size_t)(k0 + brow) * V + bn + bcol4 * 4]);
        float4 b1 = *reinterpret_cast<const float4*>(&B[(size_t)(k0 + brow + 8) * V + bn + bcol4 * 4]);

        As[acol4 * 4 + 0][arow] = a0.x;
        As[acol4 * 4 + 1][arow] = a0.y;
        As[acol4 * 4 + 2][arow] = a0.z;
        As[acol4 * 4 + 3][arow] = a0.w;
        As[acol4 * 4 + 0][arow + 64] = a1.x;
        As[acol4 * 4 + 1][arow + 64] = a1.y;
        As[acol4 * 4 + 2][arow + 64] = a1.z;
        As[acol4 * 4 + 3][arow + 64] = a1.w;
        *reinterpret_cast<float4*>(&Bs[brow][bcol4 * 4]) = b0;
        *reinterpret_cast<float4*>(&Bs[brow + 8][bcol4 * 4]) = b1;

        __syncthreads();
#pragma unroll
        for (int kk = 0; kk < FBK; ++kk) {
            float4 av0 = *reinterpret_cast<const float4*>(&As[kk][ty * FTM]);
            float4 av1 = *reinterpret_cast<const float4*>(&As[kk][ty * FTM + 4]);
            float4 bv0 = *reinterpret_cast<const float4*>(&Bs[kk][tx * FTN]);
            float4 bv1 = *reinterpret_cast<const float4*>(&Bs[kk][tx * FTN + 4]);
            float a[FTM] = {av0.x, av0.y, av0.z, av0.w, av1.x, av1.y, av1.z, av1.w};
            float b[FTN] = {bv0.x, bv0.y, bv0.z, bv0.w, bv1.x, bv1.y, bv1.z, bv1.w};
#pragma unroll
            for (int i = 0; i < FTM; ++i)
#pragma unroll
                for (int j = 0; j < FTN; ++j)
                    acc[i][j] = fmaf(a[i], b[j], acc[i][j]);
        }
        __syncthreads();
    }

#pragma unroll
    for (int i = 0; i < FTM; ++i) {
        float bv = acc[i][0];
        int bc = bn + tx * FTN;
#pragma unroll
        for (int j = 1; j < FTN; ++j) {
            float v = acc[i][j];
            int c = bn + tx * FTN + j;
            if (v > bv) { bv = v; bc = c; }
        }
        unsigned long long packed =
            ((unsigned long long)fkey(bv) << 32) |
            (unsigned long long)(0xFFFFFFFFu - (unsigned int)bc);
#pragma unroll
        for (int m = 1; m < 16; m <<= 1) {
            unsigned long long o = __shfl_xor(packed, m, 16);
            if (o > packed) packed = o;
        }
        if (tx == 0) atomicMax(&best[bm + ty * FTM + i], packed);
    }
}

__global__ void decode_kernel(const unsigned long long* __restrict__ best,
                              float* __restrict__ out, int N)
{
    int i = blockIdx.x * blockDim.x + threadIdx.x;
    if (i < N) {
        unsigned int inv = (unsigned int)(best[i] & 0xFFFFFFFFull);
        out[i] = (float)(0xFFFFFFFFu - inv);
    }
}

extern "C" void kernel_launch(void* const* d_in, const int* in_sizes, int n_in,
                              void* d_out, int out_size, void* d_ws, size_t ws_size,
                              hipStream_t stream) {
    const float* A = (const float*)d_in[0];   // x  [N, D]
    const float* B = (const float*)d_in[1];   // di [D, V]
    float* out = (float*)d_out;

    const int N = out_size;                   // 16384
    const int D = in_sizes[0] / N;            // 2048
    const int V = in_sizes[1] / D;            // 8192

    const size_t szX = (size_t)N * D * sizeof(_Float16);   // 64 MB
    const size_t szD = (size_t)D * V * sizeof(_Float16);   // 32 MB
    const size_t need = 2 * szX + 2 * szD + (size_t)N * 8;

    if (ws_size >= need) {
        char* w = (char*)d_ws;
        _Float16* Xh  = (_Float16*)(w);
        _Float16* Xl  = (_Float16*)(w + szX);
        _Float16* DhT = (_Float16*)(w + 2 * szX);
        _Float16* DlT = (_Float16*)(w + 2 * szX + szD);
        unsigned long long* best = (unsigned long long*)(w + 2 * szX + 2 * szD);

        hipMemsetAsync(best, 0, (size_t)N * 8, stream);
        prep_x_kernel<<<(int)(((size_t)N * D) / (256 * 8)), 256, 0, stream>>>(A, Xh, Xl);
        prep_di_kernel<<<dim3(V / 64, D / 32), 256, 0, stream>>>(B, DhT, DlT, D, V);
        gemm_f16x3_argmax_kernel<<<dim3(V / BN, N / BM), 256, 0, stream>>>(
            Xh, Xl, DhT, DlT, best, N, D, V);
        decode_kernel<<<(N + 255) / 256, 256, 0, stream>>>(best, out, N);
    } else {
        unsigned long long* best = (unsigned long long*)d_ws;
        hipMemsetAsync(best, 0, (size_t)N * sizeof(unsigned long long), stream);
        gemm_argmax_fp32_kernel<<<dim3(V / BN, N / BM), 256, 0, stream>>>(A, B, best, N, D, V);
        decode_kernel<<<(N + 255) / 256, 256, 0, stream>>>(best, out, N);
    }
}

// Round 3
// 1781.514 us; speedup vs baseline: 3.5770x; 3.3768x over previous
//
#include <hip/hip_runtime.h>

typedef _Float16 f16x8 __attribute__((ext_vector_type(8)));
typedef float f32x4 __attribute__((ext_vector_type(4)));

#define BM 128
#define BN 128
#define BK 64

__device__ __forceinline__ unsigned int fkey(float f) {
    unsigned int u = __float_as_uint(f);
    return u ^ ((u & 0x80000000u) ? 0xFFFFFFFFu : 0x80000000u);
}

// ============================================================
// Prep: split fp32 -> (hi, lo) f16 pairs. x kept row-major; di transposed.
// ============================================================
__global__ __launch_bounds__(256) void prep_x_kernel(
    const float* __restrict__ x, _Float16* __restrict__ Xh,
    _Float16* __restrict__ Xl)
{
    size_t base = ((size_t)blockIdx.x * 256 + threadIdx.x) * 8;
    float4 a0 = *(const float4*)(x + base);
    float4 a1 = *(const float4*)(x + base + 4);
    float v[8] = {a0.x, a0.y, a0.z, a0.w, a1.x, a1.y, a1.z, a1.w};
    f16x8 h, l;
#pragma unroll
    for (int j = 0; j < 8; ++j) {
        _Float16 hh = (_Float16)v[j];
        h[j] = hh;
        l[j] = (_Float16)(v[j] - (float)hh);   // residual exact in fp32
    }
    *(f16x8*)(Xh + base) = h;
    *(f16x8*)(Xl + base) = l;
}

__global__ __launch_bounds__(256) void prep_di_kernel(
    const float* __restrict__ di, _Float16* __restrict__ DhT,
    _Float16* __restrict__ DlT, int D, int V)
{
    int v  = blockIdx.x * 64 + (threadIdx.x & 63);
    int d0 = blockIdx.y * 32 + (threadIdx.x >> 6) * 8;
    f16x8 h, l;
#pragma unroll
    for (int j = 0; j < 8; ++j) {
        float val = di[(size_t)(d0 + j) * V + v];   // coalesced across lanes
        _Float16 hh = (_Float16)val;
        h[j] = hh;
        l[j] = (_Float16)(val - (float)hh);
    }
    *(f16x8*)(DhT + (size_t)v * D + d0) = h;
    *(f16x8*)(DlT + (size_t)v * D + d0) = l;
}

// ============================================================
// Main: 128x128 tile, BK=64 f16, 4 waves (2x2), 4x4 16x16x32 frags/wave,
// 3 MFMA terms per frag pair (ah*bh + ah*bl + al*bh).
// Staging: global_load_lds width=16, LDS linear, XOR-swizzle applied to
// the per-lane GLOBAL source address (slot ^= row&7 within 128B rows);
// ds_read applies the same XOR -> ~2-way (free) bank access.
// ============================================================
__global__ __launch_bounds__(256, 2) void gemm_f16x3_argmax_kernel(
    const _Float16* __restrict__ Xh, const _Float16* __restrict__ Xl,
    const _Float16* __restrict__ DhT, const _Float16* __restrict__ DlT,
    unsigned long long* __restrict__ best, int N, int D, int V)
{
    __shared__ __align__(16) unsigned char sm[4 * 128 * 128];  // 64 KB: Ah,Al,Bh,Bl

    const int tid = threadIdx.x;
    const int w = tid >> 6, lane = tid & 63;
    const int wr = w >> 1, wc = w & 1;
    const int lm = lane & 15, lg = lane >> 4;

    // bijective XCD-aware swizzle (nwg = 8192, divisible by 8)
    const int nwg = gridDim.x, cpx = nwg >> 3;
    const int bid = blockIdx.x;
    const int swz = (bid & 7) * cpx + (bid >> 3);
    const int bm = (swz >> 6) * BM;      // V/BN = 64 tiles along x
    const int bn = (swz & 63) * BN;

    // staging lane geometry: chunk = 8 rows x 128B; lane l -> row c*8+(l>>3),
    // physical 16B slot l&7, logical slot (l&7)^(l>>3) (pre-swizzled source)
    const int ri  = lane >> 3;
    const int sl8 = ((lane & 7) ^ ri) * 8;   // f16 offset within row

    const _Float16* srcs[4] = {
        Xh  + (size_t)(bm + ri) * D + sl8,
        Xl  + (size_t)(bm + ri) * D + sl8,
        DhT + (size_t)(bn + ri) * D + sl8,
        DlT + (size_t)(bn + ri) * D + sl8 };

    f32x4 acc[4][4];
#pragma unroll
    for (int fm = 0; fm < 4; ++fm)
#pragma unroll
        for (int fn = 0; fn < 4; ++fn) acc[fm][fn] = (f32x4){0.f, 0.f, 0.f, 0.f};

    const int nt = D / BK;   // 32
#pragma unroll 1
    for (int t = 0; t < nt; ++t) {
        const int k0 = t * BK;
        // ---- stage 4 tiles x 16KB via global_load_lds (no staging VGPRs) ----
#pragma unroll
        for (int tt = 0; tt < 4; ++tt) {
#pragma unroll
            for (int i = 0; i < 4; ++i) {
                const int c = w + i * 4;             // wave-uniform chunk 0..15
                __builtin_amdgcn_global_load_lds(
                    (const __attribute__((address_space(1))) void*)
                        (srcs[tt] + (size_t)(c * 8) * D + k0),
                    (__attribute__((address_space(3))) void*)
                        (sm + tt * 16384 + c * 1024),
                    16, 0, 0);
            }
        }
        __syncthreads();   // compiler drains vmcnt before s_barrier

        // ---- compute: 2 K-halves x 48 MFMAs ----
#pragma unroll
        for (int kk = 0; kk < 2; ++kk) {
            f16x8 ah[4], al[4], bh[4], bl[4];
            const int so = ((kk * 4 + lg) ^ (lm & 7)) * 16;
#pragma unroll
            for (int f = 0; f < 4; ++f) {
                const int ar = wr * 64 + f * 16 + lm;
                const int br = wc * 64 + f * 16 + lm;
                ah[f] = *(const f16x8*)(sm +         ar * 128 + so);
                al[f] = *(const f16x8*)(sm + 16384 + ar * 128 + so);
                bh[f] = *(const f16x8*)(sm + 32768 + br * 128 + so);
                bl[f] = *(const f16x8*)(sm + 49152 + br * 128 + so);
            }
#pragma unroll
            for (int fm = 0; fm < 4; ++fm)
#pragma unroll
                for (int fn = 0; fn < 4; ++fn) {
                    acc[fm][fn] = __builtin_amdgcn_mfma_f32_16x16x32_f16(ah[fm], bh[fn], acc[fm][fn], 0, 0, 0);
                    acc[fm][fn] = __builtin_amdgcn_mfma_f32_16x16x32_f16(ah[fm], bl[fn], acc[fm][fn], 0, 0, 0);
                    acc[fm][fn] = __builtin_amdgcn_mfma_f32_16x16x32_f16(al[fm], bh[fn], acc[fm][fn], 0, 0, 0);
                }
        }
        if (t + 1 < nt) __syncthreads();   // LDS reusable for next stage
    }

    // ---- fused argmax epilogue ----
    // C/D layout: col = lane&15, row = (lane>>4)*4 + j
#pragma unroll
    for (int fm = 0; fm < 4; ++fm)
#pragma unroll
        for (int j = 0; j < 4; ++j) {
            const int row = bm + wr * 64 + fm * 16 + lg * 4 + j;
            float bv = acc[fm][0][j];
            int   bc = bn + wc * 64 + lm;
#pragma unroll
            for (int fn = 1; fn < 4; ++fn) {
                float vv = acc[fm][fn][j];
                int   cc = bn + wc * 64 + fn * 16 + lm;
                if (vv > bv) { bv = vv; bc = cc; }   // strict > keeps lowest col
            }
            unsigned long long packed =
                ((unsigned long long)fkey(bv) << 32) |
                (unsigned long long)(0xFFFFFFFFu - (unsigned int)bc);
#pragma unroll
            for (int m = 1; m < 16; m <<= 1) {
                unsigned long long o = __shfl_xor(packed, m, 16);
                if (o > packed) packed = o;
            }
            if (lm == 0) atomicMax(&best[row], packed);
        }
}

// ============================================================
// Fallback (small ws): round-1 fp32 kernel, known-passing.
// ============================================================
#define FBK 16
#define FTM 8
#define FTN 8

__global__ __launch_bounds__(256) void gemm_argmax_fp32_kernel(
    const float* __restrict__ A, const float* __restrict__ B,
    unsigned long long* __restrict__ best, int N, int D, int V)
{
    __shared__ float As[FBK][BM + 4];
    __shared__ float Bs[FBK][BN + 4];

    const int tid = threadIdx.x;
    const int tx = tid & 15;
    const int ty = tid >> 4;
    const int bm = blockIdx.y * BM;
    const int bn = blockIdx.x * BN;

    const int arow  = tid >> 2;
    const int acol4 = tid & 3;
    const int brow  = tid >> 5;
    const int bcol4 = tid & 31;

    float acc[FTM][FTN];
#pragma unroll
    for (int i = 0; i < FTM; ++i)
#pragma unroll
        for (int j = 0; j < FTN; ++j) acc[i][j] = 0.0f;

    for (int k0 = 0; k0 < D; k0 += FBK) {
        float4 a0 = *reinterpret_cast<const float4*>(&A[(size_t)(bm + arow) * D + k0 + acol4 * 4]);
        float4 a1 = *reinterpret_cast<const float4*>(&A[(size_t)(bm + arow + 64) * D + k0 + acol4 * 4]);
        float4 b0 = *reinterpret_cast<const float4*>(&B[(size_t)(k0 + brow) * V + bn + bcol4 * 4]);
        float4 b1 = *reinterpret_cast<const float4*>(&B[(size_t)(k0 + brow + 8) * V + bn + bcol4 * 4]);

        As[acol4 * 4 + 0][arow] = a0.x;
        As[acol4 * 4 + 1][arow] = a0.y;
        As[acol4 * 4 + 2][arow] = a0.z;
        As[acol4 * 4 + 3][arow] = a0.w;
        As[acol4 * 4 + 0][arow + 64] = a1.x;
        As[acol4 * 4 + 1][arow + 64] = a1.y;
        As[acol4 * 4 + 2][arow + 64] = a1.z;
        As[acol4 * 4 + 3][arow + 64] = a1.w;
        *reinterpret_cast<float4*>(&Bs[brow][bcol4 * 4]) = b0;
        *reinterpret_cast<float4*>(&Bs[brow + 8][bcol4 * 4]) = b1;

        __syncthreads();
#pragma unroll
        for (int kk = 0; kk < FBK; ++kk) {
            float4 av0 = *reinterpret_cast<const float4*>(&As[kk][ty * FTM]);
            float4 av1 = *reinterpret_cast<const float4*>(&As[kk][ty * FTM + 4]);
            float4 bv0 = *reinterpret_cast<const float4*>(&Bs[kk][tx * FTN]);
            float4 bv1 = *reinterpret_cast<const float4*>(&Bs[kk][tx * FTN + 4]);
            float a[FTM] = {av0.x, av0.y, av0.z, av0.w, av1.x, av1.y, av1.z, av1.w};
            float b[FTN] = {bv0.x, bv0.y, bv0.z, bv0.w, bv1.x, bv1.y, bv1.z, bv1.w};
#pragma unroll
            for (int i = 0; i < FTM; ++i)
#pragma unroll
                for (int j = 0; j < FTN; ++j)
                    acc[i][j] = fmaf(a[i], b[j], acc[i][j]);
        }
        __syncthreads();
    }

#pragma unroll
    for (int i = 0; i < FTM; ++i) {
        float bv = acc[i][0];
        int bc = bn + tx * FTN;
#pragma unroll
        for (int j = 1; j < FTN; ++j) {
            float v = acc[i][j];
            int c = bn + tx * FTN + j;
            if (v > bv) { bv = v; bc = c; }
        }
        unsigned long long packed =
            ((unsigned long long)fkey(bv) << 32) |
            (unsigned long long)(0xFFFFFFFFu - (unsigned int)bc);
#pragma unroll
        for (int m = 1; m < 16; m <<= 1) {
            unsigned long long o = __shfl_xor(packed, m, 16);
            if (o > packed) packed = o;
        }
        if (tx == 0) atomicMax(&best[bm + ty * FTM + i], packed);
    }
}

__global__ void decode_kernel(const unsigned long long* __restrict__ best,
                              float* __restrict__ out, int N)
{
    int i = blockIdx.x * blockDim.x + threadIdx.x;
    if (i < N) {
        unsigned int inv = (unsigned int)(best[i] & 0xFFFFFFFFull);
        out[i] = (float)(0xFFFFFFFFu - inv);
    }
}

extern "C" void kernel_launch(void* const* d_in, const int* in_sizes, int n_in,
                              void* d_out, int out_size, void* d_ws, size_t ws_size,
                              hipStream_t stream) {
    const float* A = (const float*)d_in[0];   // x  [N, D]
    const float* B = (const float*)d_in[1];   // di [D, V]
    float* out = (float*)d_out;

    const int N = out_size;                   // 16384
    const int D = in_sizes[0] / N;            // 2048
    const int V = in_sizes[1] / D;            // 8192

    const size_t szX = (size_t)N * D * sizeof(_Float16);   // 64 MB
    const size_t szD = (size_t)D * V * sizeof(_Float16);   // 32 MB
    const size_t need = 2 * szX + 2 * szD + (size_t)N * 8;

    if (ws_size >= need) {
        char* wsp = (char*)d_ws;
        _Float16* Xh  = (_Float16*)(wsp);
        _Float16* Xl  = (_Float16*)(wsp + szX);
        _Float16* DhT = (_Float16*)(wsp + 2 * szX);
        _Float16* DlT = (_Float16*)(wsp + 2 * szX + szD);
        unsigned long long* best = (unsigned long long*)(wsp + 2 * szX + 2 * szD);

        hipMemsetAsync(best, 0, (size_t)N * 8, stream);
        prep_x_kernel<<<(int)(((size_t)N * D) / (256 * 8)), 256, 0, stream>>>(A, Xh, Xl);
        prep_di_kernel<<<dim3(V / 64, D / 32), 256, 0, stream>>>(B, DhT, DlT, D, V);
        gemm_f16x3_argmax_kernel<<<(N / BM) * (V / BN), 256, 0, stream>>>(
            Xh, Xl, DhT, DlT, best, N, D, V);
        decode_kernel<<<(N + 255) / 256, 256, 0, stream>>>(best, out, N);
    } else {
        unsigned long long* best = (unsigned long long*)d_ws;
        hipMemsetAsync(best, 0, (size_t)N * sizeof(unsigned long long), stream);
        gemm_argmax_fp32_kernel<<<dim3(V / BN, N / BM), 256, 0, stream>>>(A, B, best, N, D, V);
        decode_kernel<<<(N + 255) / 256, 256, 0, stream>>>(best, out, N);
    }
}

// Round 4
// 1768.121 us; speedup vs baseline: 3.6041x; 1.0076x over previous
//
#include <hip/hip_runtime.h>

typedef _Float16 f16x8 __attribute__((ext_vector_type(8)));
typedef float f32x4 __attribute__((ext_vector_type(4)));

__device__ __forceinline__ unsigned int fkey(float f) {
    unsigned int u = __float_as_uint(f);
    return u ^ ((u & 0x80000000u) ? 0xFFFFFFFFu : 0x80000000u);
}

// ============================================================
// Prep: split fp32 -> (hi, lo) f16 pairs. x kept row-major; di transposed.
// ============================================================
__global__ __launch_bounds__(256) void prep_x_kernel(
    const float* __restrict__ x, _Float16* __restrict__ Xh,
    _Float16* __restrict__ Xl)
{
    size_t base = ((size_t)blockIdx.x * 256 + threadIdx.x) * 8;
    float4 a0 = *(const float4*)(x + base);
    float4 a1 = *(const float4*)(x + base + 4);
    float v[8] = {a0.x, a0.y, a0.z, a0.w, a1.x, a1.y, a1.z, a1.w};
    f16x8 h, l;
#pragma unroll
    for (int j = 0; j < 8; ++j) {
        _Float16 hh = (_Float16)v[j];
        h[j] = hh;
        l[j] = (_Float16)(v[j] - (float)hh);   // residual exact in fp32
    }
    *(f16x8*)(Xh + base) = h;
    *(f16x8*)(Xl + base) = l;
}

__global__ __launch_bounds__(256) void prep_di_kernel(
    const float* __restrict__ di, _Float16* __restrict__ DhT,
    _Float16* __restrict__ DlT, int D, int V)
{
    int v  = blockIdx.x * 64 + (threadIdx.x & 63);
    int d0 = blockIdx.y * 32 + (threadIdx.x >> 6) * 8;
    f16x8 h, l;
#pragma unroll
    for (int j = 0; j < 8; ++j) {
        float val = di[(size_t)(d0 + j) * V + v];   // coalesced across lanes
        _Float16 hh = (_Float16)val;
        h[j] = hh;
        l[j] = (_Float16)(val - (float)hh);
    }
    *(f16x8*)(DhT + (size_t)v * D + d0) = h;
    *(f16x8*)(DlT + (size_t)v * D + d0) = l;
}

// ============================================================
// Main: 256x256 tile, BK=32, 8 waves (2x4), per-wave 128x64 output,
// 3-term f16 MFMA (ah*bh + ah*bl + al*bh), 4-phase K-tile schedule,
// double-buffered LDS (2 x 64KB dynamic), counted vmcnt (drain once per
// tile after ~3.5 phases of compute), raw s_barrier + setprio.
// Staging: global_load_lds w=16, linear LDS dest, XOR swizzle applied to
// per-lane GLOBAL source (slot ^= row&3 within 64B rows); ds_read applies
// the same XOR -> ~2-way bank access (free).
// ============================================================
__global__ __launch_bounds__(512, 2) void gemm_f16x3_argmax_256(
    const _Float16* __restrict__ Xh, const _Float16* __restrict__ Xl,
    const _Float16* __restrict__ DhT, const _Float16* __restrict__ DlT,
    unsigned long long* __restrict__ best, int N, int D, int V)
{
    extern __shared__ __align__(16) unsigned char sm[];   // 2 x 65536

    const int tid = threadIdx.x;
    const int w = tid >> 6, lane = tid & 63;
    const int wr = w >> 2, wc = w & 3;          // 2x4 wave grid
    const int lm = lane & 15, lg = lane >> 4;

    // bijective XCD swizzle (2048 blocks, 2048 % 8 == 0)
    const int cpx = gridDim.x >> 3;
    const int swz = (blockIdx.x & 7) * cpx + (blockIdx.x >> 3);
    const int bm = (swz >> 5) * 256;            // 64 m-tiles
    const int bn = (swz & 31) * 256;            // 32 n-tiles

    // staging geometry: chunk = 16 rows x 64B (1KB), lane l -> row l>>2,
    // phys slot l&3; source reads logical slot (l&3)^(row&3) (pre-swizzle)
    const int srow = lane >> 2;
    const int ssl  = ((lane & 3) ^ (srow & 3)) * 8;   // f16 offset in row

    const _Float16* opsrc[4] = {
        Xh  + (size_t)bm * D,
        Xl  + (size_t)bm * D,
        DhT + (size_t)bn * D,
        DlT + (size_t)bn * D };

    // wave w stages chunks g = w*8+i : operand g>>4, chunk g&15
    auto stage = [&](int buf, int k0) {
#pragma unroll
        for (int i = 0; i < 8; ++i) {
            const int g = w * 8 + i;
            const int tt = g >> 4, c = g & 15;
            __builtin_amdgcn_global_load_lds(
                (const __attribute__((address_space(1))) void*)
                    (opsrc[tt] + (size_t)(c * 16 + srow) * D + k0 + ssl),
                (__attribute__((address_space(3))) void*)
                    (sm + buf * 65536 + tt * 16384 + c * 1024),
                16, 0, 0);
        }
    };
    // read one f16x8 frag: operand op, tile-row r, k-slot lg
    auto lda = [&](int buf, int op, int r) -> f16x8 {
        return *(const f16x8*)(sm + buf * 65536 + op * 16384 + r * 64 +
                               ((lg ^ (r & 3)) * 16));
    };

    f32x4 acc[8][4];
#pragma unroll
    for (int fm = 0; fm < 8; ++fm)
#pragma unroll
        for (int fn = 0; fn < 4; ++fn) acc[fm][fn] = (f32x4){0.f, 0.f, 0.f, 0.f};

    const int nt = D / 32;   // 64
    int cbuf = 0;

    stage(0, 0);
    asm volatile("s_waitcnt vmcnt(0)" ::: "memory");
    __builtin_amdgcn_s_barrier();

#pragma unroll 1
    for (int t = 0; t < nt; ++t) {
        f16x8 bh[4], bl[4];
        // ---------------- phase 0 ----------------
#pragma unroll
        for (int fn = 0; fn < 4; ++fn) {
            const int rb = wc * 64 + fn * 16 + lm;
            bh[fn] = lda(cbuf, 2, rb);
            bl[fn] = lda(cbuf, 3, rb);
        }
        {
            const int r0 = wr * 128 + 0 * 16 + lm;
            const int r1 = wr * 128 + 1 * 16 + lm;
            f16x8 a0h = lda(cbuf, 0, r0), a0l = lda(cbuf, 1, r0);
            f16x8 a1h = lda(cbuf, 0, r1), a1l = lda(cbuf, 1, r1);
            if (t + 1 < nt) stage(cbuf ^ 1, (t + 1) * 32);
            asm volatile("" ::: "memory");
            __builtin_amdgcn_s_barrier();
            __builtin_amdgcn_s_setprio(1);
#pragma unroll
            for (int fn = 0; fn < 4; ++fn) {
                acc[0][fn] = __builtin_amdgcn_mfma_f32_16x16x32_f16(a0h, bh[fn], acc[0][fn], 0, 0, 0);
                acc[0][fn] = __builtin_amdgcn_mfma_f32_16x16x32_f16(a0h, bl[fn], acc[0][fn], 0, 0, 0);
                acc[0][fn] = __builtin_amdgcn_mfma_f32_16x16x32_f16(a0l, bh[fn], acc[0][fn], 0, 0, 0);
                acc[1][fn] = __builtin_amdgcn_mfma_f32_16x16x32_f16(a1h, bh[fn], acc[1][fn], 0, 0, 0);
                acc[1][fn] = __builtin_amdgcn_mfma_f32_16x16x32_f16(a1h, bl[fn], acc[1][fn], 0, 0, 0);
                acc[1][fn] = __builtin_amdgcn_mfma_f32_16x16x32_f16(a1l, bh[fn], acc[1][fn], 0, 0, 0);
            }
            __builtin_amdgcn_s_setprio(0);
            asm volatile("" ::: "memory");
            __builtin_amdgcn_s_barrier();
        }
        // ---------------- phases 1..3 ----------------
#pragma unroll
        for (int p = 1; p < 4; ++p) {
            const int fm0 = 2 * p;
            const int r0 = wr * 128 + fm0 * 16 + lm;
            const int r1 = wr * 128 + (fm0 + 1) * 16 + lm;
            f16x8 a0h = lda(cbuf, 0, r0), a0l = lda(cbuf, 1, r0);
            f16x8 a1h = lda(cbuf, 0, r1), a1l = lda(cbuf, 1, r1);
            asm volatile("" ::: "memory");
            __builtin_amdgcn_s_barrier();
            __builtin_amdgcn_s_setprio(1);
#pragma unroll
            for (int fn = 0; fn < 4; ++fn) {
                acc[fm0][fn]     = __builtin_amdgcn_mfma_f32_16x16x32_f16(a0h, bh[fn], acc[fm0][fn], 0, 0, 0);
                acc[fm0][fn]     = __builtin_amdgcn_mfma_f32_16x16x32_f16(a0h, bl[fn], acc[fm0][fn], 0, 0, 0);
                acc[fm0][fn]     = __builtin_amdgcn_mfma_f32_16x16x32_f16(a0l, bh[fn], acc[fm0][fn], 0, 0, 0);
                acc[fm0 + 1][fn] = __builtin_amdgcn_mfma_f32_16x16x32_f16(a1h, bh[fn], acc[fm0 + 1][fn], 0, 0, 0);
                acc[fm0 + 1][fn] = __builtin_amdgcn_mfma_f32_16x16x32_f16(a1h, bl[fn], acc[fm0 + 1][fn], 0, 0, 0);
                acc[fm0 + 1][fn] = __builtin_amdgcn_mfma_f32_16x16x32_f16(a1l, bh[fn], acc[fm0 + 1][fn], 0, 0, 0);
            }
            __builtin_amdgcn_s_setprio(0);
            if (p == 3) asm volatile("s_waitcnt vmcnt(0)" ::: "memory");
            asm volatile("" ::: "memory");
            __builtin_amdgcn_s_barrier();
        }
        cbuf ^= 1;
    }

    // ---- fused argmax epilogue ----
    // C/D layout: col = lane&15, row = (lane>>4)*4 + j
#pragma unroll
    for (int fm = 0; fm < 8; ++fm)
#pragma unroll
        for (int j = 0; j < 4; ++j) {
            const int row = bm + wr * 128 + fm * 16 + lg * 4 + j;
            float bv = acc[fm][0][j];
            int   bc = bn + wc * 64 + lm;
#pragma unroll
            for (int fn = 1; fn < 4; ++fn) {
                float vv = acc[fm][fn][j];
                int   cc = bn + wc * 64 + fn * 16 + lm;
                if (vv > bv) { bv = vv; bc = cc; }   // strict > keeps lowest col
            }
            unsigned long long packed =
                ((unsigned long long)fkey(bv) << 32) |
                (unsigned long long)(0xFFFFFFFFu - (unsigned int)bc);
#pragma unroll
            for (int m = 1; m < 16; m <<= 1) {
                unsigned long long o = __shfl_xor(packed, m, 16);
                if (o > packed) packed = o;
            }
            if (lm == 0) atomicMax(&best[row], packed);
        }
}

// ============================================================
// Fallback (small ws): round-1 fp32 kernel, known-passing.
// ============================================================
#define FBK 16
#define FTM 8
#define FTN 8

__global__ __launch_bounds__(256) void gemm_argmax_fp32_kernel(
    const float* __restrict__ A, const float* __restrict__ B,
    unsigned long long* __restrict__ best, int N, int D, int V)
{
    __shared__ float As[FBK][128 + 4];
    __shared__ float Bs[FBK][128 + 4];

    const int tid = threadIdx.x;
    const int tx = tid & 15;
    const int ty = tid >> 4;
    const int bm = blockIdx.y * 128;
    const int bn = blockIdx.x * 128;

    const int arow  = tid >> 2;
    const int acol4 = tid & 3;
    const int brow  = tid >> 5;
    const int bcol4 = tid & 31;

    float acc[FTM][FTN];
#pragma unroll
    for (int i = 0; i < FTM; ++i)
#pragma unroll
        for (int j = 0; j < FTN; ++j) acc[i][j] = 0.0f;

    for (int k0 = 0; k0 < D; k0 += FBK) {
        float4 a0 = *reinterpret_cast<const float4*>(&A[(size_t)(bm + arow) * D + k0 + acol4 * 4]);
        float4 a1 = *reinterpret_cast<const float4*>(&A[(size_t)(bm + arow + 64) * D + k0 + acol4 * 4]);
        float4 b0 = *reinterpret_cast<const float4*>(&B[(size_t)(k0 + brow) * V + bn + bcol4 * 4]);
        float4 b1 = *reinterpret_cast<const float4*>(&B[(size_t)(k0 + brow + 8) * V + bn + bcol4 * 4]);

        As[acol4 * 4 + 0][arow] = a0.x;
        As[acol4 * 4 + 1][arow] = a0.y;
        As[acol4 * 4 + 2][arow] = a0.z;
        As[acol4 * 4 + 3][arow] = a0.w;
        As[acol4 * 4 + 0][arow + 64] = a1.x;
        As[acol4 * 4 + 1][arow + 64] = a1.y;
        As[acol4 * 4 + 2][arow + 64] = a1.z;
        As[acol4 * 4 + 3][arow + 64] = a1.w;
        *reinterpret_cast<float4*>(&Bs[brow][bcol4 * 4]) = b0;
        *reinterpret_cast<float4*>(&Bs[brow + 8][bcol4 * 4]) = b1;

        __syncthreads();
#pragma unroll
        for (int kk = 0; kk < FBK; ++kk) {
            float4 av0 = *reinterpret_cast<const float4*>(&As[kk][ty * FTM]);
            float4 av1 = *reinterpret_cast<const float4*>(&As[kk][ty * FTM + 4]);
            float4 bv0 = *reinterpret_cast<const float4*>(&Bs[kk][tx * FTN]);
            float4 bv1 = *reinterpret_cast<const float4*>(&Bs[kk][tx * FTN + 4]);
            float a[FTM] = {av0.x, av0.y, av0.z, av0.w, av1.x, av1.y, av1.z, av1.w};
            float b[FTN] = {bv0.x, bv0.y, bv0.z, bv0.w, bv1.x, bv1.y, bv1.z, bv1.w};
#pragma unroll
            for (int i = 0; i < FTM; ++i)
#pragma unroll
                for (int j = 0; j < FTN; ++j)
                    acc[i][j] = fmaf(a[i], b[j], acc[i][j]);
        }
        __syncthreads();
    }

#pragma unroll
    for (int i = 0; i < FTM; ++i) {
        float bv = acc[i][0];
        int bc = bn + tx * FTN;
#pragma unroll
        for (int j = 1; j < FTN; ++j) {
            float v = acc[i][j];
            int c = bn + tx * FTN + j;
            if (v > bv) { bv = v; bc = c; }
        }
        unsigned long long packed =
            ((unsigned long long)fkey(bv) << 32) |
            (unsigned long long)(0xFFFFFFFFu - (unsigned int)bc);
#pragma unroll
        for (int m = 1; m < 16; m <<= 1) {
            unsigned long long o = __shfl_xor(packed, m, 16);
            if (o > packed) packed = o;
        }
        if (tx == 0) atomicMax(&best[bm + ty * FTM + i], packed);
    }
}

__global__ void decode_kernel(const unsigned long long* __restrict__ best,
                              float* __restrict__ out, int N)
{
    int i = blockIdx.x * blockDim.x + threadIdx.x;
    if (i < N) {
        unsigned int inv = (unsigned int)(best[i] & 0xFFFFFFFFull);
        out[i] = (float)(0xFFFFFFFFu - inv);
    }
}

extern "C" void kernel_launch(void* const* d_in, const int* in_sizes, int n_in,
                              void* d_out, int out_size, void* d_ws, size_t ws_size,
                              hipStream_t stream) {
    const float* A = (const float*)d_in[0];   // x  [N, D]
    const float* B = (const float*)d_in[1];   // di [D, V]
    float* out = (float*)d_out;

    const int N = out_size;                   // 16384
    const int D = in_sizes[0] / N;            // 2048
    const int V = in_sizes[1] / D;            // 8192

    const size_t szX = (size_t)N * D * sizeof(_Float16);   // 64 MB
    const size_t szD = (size_t)D * V * sizeof(_Float16);   // 32 MB
    const size_t need = 2 * szX + 2 * szD + (size_t)N * 8;

    if (ws_size >= need) {
        char* wsp = (char*)d_ws;
        _Float16* Xh  = (_Float16*)(wsp);
        _Float16* Xl  = (_Float16*)(wsp + szX);
        _Float16* DhT = (_Float16*)(wsp + 2 * szX);
        _Float16* DlT = (_Float16*)(wsp + 2 * szX + szD);
        unsigned long long* best = (unsigned long long*)(wsp + 2 * szX + 2 * szD);

        static int attr_done = 0;   // host-side, deterministic, idempotent
        if (!attr_done) {
            hipFuncSetAttribute((const void*)gemm_f16x3_argmax_256,
                                hipFuncAttributeMaxDynamicSharedMemorySize, 131072);
            attr_done = 1;
        }

        hipMemsetAsync(best, 0, (size_t)N * 8, stream);
        prep_x_kernel<<<(int)(((size_t)N * D) / (256 * 8)), 256, 0, stream>>>(A, Xh, Xl);
        prep_di_kernel<<<dim3(V / 64, D / 32), 256, 0, stream>>>(B, DhT, DlT, D, V);
        gemm_f16x3_argmax_256<<<(N / 256) * (V / 256), 512, 131072, stream>>>(
            Xh, Xl, DhT, DlT, best, N, D, V);
        decode_kernel<<<(N + 255) / 256, 256, 0, stream>>>(best, out, N);
    } else {
        unsigned long long* best = (unsigned long long*)d_ws;
        hipMemsetAsync(best, 0, (size_t)N * sizeof(unsigned long long), stream);
        gemm_argmax_fp32_kernel<<<dim3(V / 128, N / 128), 256, 0, stream>>>(A, B, best, N, D, V);
        decode_kernel<<<(N + 255) / 256, 256, 0, stream>>>(best, out, N);
    }
}